// Round 11
// baseline (171.825 us; speedup 1.0000x reference)
//
#include <hip/hip_runtime.h>
#include <hip/hip_bf16.h>

#define B_ROWS 4096
#define N2     8192
#define DIM    128
#define LN2    0.6931471805599453f
// sqrt((1/T)*log2(e)): rn pre-scaled so the MFMA accumulator IS the exp2 arg.
#define S_SCALE 1.6986436f

typedef __attribute__((ext_vector_type(8))) short bf16x8;
typedef __attribute__((ext_vector_type(4))) float f32x4;

#if __has_builtin(__builtin_amdgcn_exp2f)
#define EXP2F(x) __builtin_amdgcn_exp2f(x)
#else
#define EXP2F(x) __expf((x) * LN2)   // native v_exp path
#endif
#if __has_builtin(__builtin_amdgcn_logf)
#define LOG2F_FAST(x) __builtin_amdgcn_logf(x)   // log2
#else
#define LOG2F_FAST(x) log2f(x)
#endif

static __device__ __forceinline__ unsigned short f2bf(float f) {
    union { float f; unsigned int u; } v; v.f = f;
    unsigned int u = v.u;
    return (unsigned short)((u + 0x7fffu + ((u >> 16) & 1u)) >> 16);
}
static __device__ __forceinline__ float bf2f(unsigned short s) {
    union { unsigned int u; float f; } v; v.u = ((unsigned int)s) << 16;
    return v.f;
}
static __device__ __forceinline__ void gload_lds16(const void* g, void* l) {
    __builtin_amdgcn_global_load_lds(
        (const __attribute__((address_space(1))) void*)g,
        (__attribute__((address_space(3))) void*)l, 16, 0, 0);
}

// K1: one wave per row -> L2-normalize, scale by S_SCALE, write bf16.
// selfexp[row] = exp2(<rn_row, rn_row>); zero out[0].
__global__ __launch_bounds__(256) void nk_normalize(
        const float* __restrict__ zi, const float* __restrict__ zj,
        unsigned short* __restrict__ rn, float* __restrict__ selfexp,
        float* __restrict__ out) {
    int gtid = blockIdx.x * 256 + threadIdx.x;
    if (gtid == 0) out[0] = 0.0f;
    int row  = gtid >> 6;
    int lane = threadIdx.x & 63;
    const float* src = (row < B_ROWS) ? (zi + (size_t)row * DIM)
                                      : (zj + (size_t)(row - B_ROWS) * DIM);
    float2 v = reinterpret_cast<const float2*>(src)[lane];
    float ss = v.x * v.x + v.y * v.y;
#pragma unroll
    for (int m = 1; m < 64; m <<= 1) ss += __shfl_xor(ss, m);
    float scale = S_SCALE / fmaxf(sqrtf(ss), 1e-8f);
    ushort2 o;
    o.x = f2bf(v.x * scale);
    o.y = f2bf(v.y * scale);
    reinterpret_cast<ushort2*>(rn + (size_t)row * DIM)[lane] = o;
    float a = bf2f(o.x), b = bf2f(o.y);
    float sd = a * a + b * b;
#pragma unroll
    for (int m = 1; m < 64; m <<= 1) sd += __shfl_xor(sd, m);
    if (lane == 0) selfexp[row] = EXP2F(sd);
}

// K2: part_out[bc][i] = sum_{j in chunk bc} exp2(acc_ij) (diag included).
// Grid 1024 = 32 row-panels(256 rows) x 32 col-chunks(256 cols). Block 256
// thr = 4 waves; wave = 64 rows (af[4][4]) -> halves per-CU LDS-read traffic
// vs the 32-row-wave shape while keeping 4 blocks/CU. B staged to LDS in
// 64-col (16 KB) double-buffered tiles via global_load_lds with involutive
// XOR swizzle f(L)=L^(((L>>8)&7)<<4) on the per-lane GLOBAL source (LDS dest
// stays linear per-wave) and on the ds_read address. Strip body and T4
// counted-vmcnt barrier protocol VERBATIM from the round-10 kernel.
__global__ __launch_bounds__(256, 4) void nk_simloss(
        const unsigned short* __restrict__ rn, float* __restrict__ part_out) {
    __shared__ char lds[2][16384];
    const int tid = threadIdx.x;
    const int bi = blockIdx.x >> 5;   // row panel 0..31 (256 rows)
    const int bc = blockIdx.x & 31;   // col chunk 0..31 (256 cols)
    const int w = tid >> 6, lane = tid & 63;
    const int lc = lane & 15, lg = lane >> 4;
    const int i0 = bi * 256 + w * 64;

    // persistent A fragments: 64 rows x K=128
    const unsigned short* abase = rn + (size_t)(i0 + lc) * DIM + lg * 8;
    bf16x8 af[4][4];
#pragma unroll
    for (int mi = 0; mi < 4; ++mi)
#pragma unroll
        for (int ks = 0; ks < 4; ++ks)
            af[mi][ks] = *reinterpret_cast<const bf16x8*>(
                abase + (size_t)mi * 16 * DIM + ks * 32);

    const char* gsrc = (const char*)rn + (size_t)bc * 256 * 256;  // chunk's B panel

#define STAGE(b, t)                                                           \
    do {                                                                      \
        _Pragma("unroll") for (int k = 0; k < 4; ++k) {                       \
            int L  = k * 4096 + tid * 16;                                     \
            int Ls = L ^ (((L >> 8) & 7) << 4);                               \
            gload_lds16(gsrc + (size_t)(t) * 16384 + Ls,                      \
                        &lds[b][k * 4096 + (tid & 192) * 16]);                \
        }                                                                     \
    } while (0)

    float part[4][4];
#pragma unroll
    for (int mi = 0; mi < 4; ++mi)
#pragma unroll
        for (int p = 0; p < 4; ++p) part[mi][p] = 0.f;

    STAGE(0, 0);

#pragma unroll 1
    for (int t = 0; t < 4; ++t) {
        const int cur = t & 1;
        // (1) all waves done READING lds[cur^1] (previous tile) -> safe to
        // overwrite it. No vmcnt drain here.
        __builtin_amdgcn_s_barrier();
        __builtin_amdgcn_sched_barrier(0);
        if (t < 3) {
            STAGE(cur ^ 1, t + 1);   // 4 loads/thread now in flight
            // wait for tile t's 4 loads (issued last iter); t+1's 4 remain.
            asm volatile("s_waitcnt vmcnt(4)" ::: "memory");
        } else {
            asm volatile("s_waitcnt vmcnt(0)" ::: "memory");
        }
        // (2) every wave has retired ITS OWN tile-t loads -> lds[cur] fully
        // staged for everyone past this barrier.
        __builtin_amdgcn_s_barrier();
        __builtin_amdgcn_sched_barrier(0);
        const char* tb = lds[cur];
#pragma unroll
        for (int s = 0; s < 4; ++s) {          // 4 strips of 16 cols
            bf16x8 bf[4];
#pragma unroll
            for (int ks = 0; ks < 4; ++ks) {
                int r = s * 16 + lc;
                int a = r * 256 + ks * 64 + lg * 16;
                a ^= (r & 7) << 4;
                bf[ks] = *reinterpret_cast<const bf16x8*>(tb + a);
            }
            f32x4 acc[4];
#pragma unroll
            for (int mi = 0; mi < 4; ++mi) acc[mi] = (f32x4){0.f, 0.f, 0.f, 0.f};
#pragma unroll
            for (int ks = 0; ks < 4; ++ks)
#pragma unroll
                for (int mi = 0; mi < 4; ++mi)
                    acc[mi] = __builtin_amdgcn_mfma_f32_16x16x32_bf16(
                        af[mi][ks], bf[ks], acc[mi], 0, 0, 0);
#pragma unroll
            for (int mi = 0; mi < 4; ++mi)
#pragma unroll
                for (int p = 0; p < 4; ++p)
                    part[mi][p] += EXP2F(acc[mi][p]);
        }
    }
#undef STAGE

    // 16-lane reduce over cols (lc), store per-row partial for this chunk.
#pragma unroll
    for (int mi = 0; mi < 4; ++mi)
#pragma unroll
        for (int p = 0; p < 4; ++p) {
            float v = part[mi][p];
#pragma unroll
            for (int m = 1; m < 16; m <<= 1) v += __shfl_xor(v, m);
            if (lc == 0)
                part_out[(size_t)bc * N2 + i0 + mi * 16 + lg * 4 + p] = v;
        }
}

// K3: loss = (ln2/N2) * sum_i [ log2(sum_c part[c][i] - selfexp_i) - d_i ],
// d_i = <rn_i, rn_{i^B}> in the scaled metric (ln2*d = 2*pos).
// 32 partial planes: lane lc sums planes lc and lc+16 before the reduce.
__global__ __launch_bounds__(256) void nk_finalize(
        const unsigned short* __restrict__ rn, const float* __restrict__ part,
        const float* __restrict__ selfexp, float* __restrict__ out) {
    int wid = threadIdx.x >> 6, lane = threadIdx.x & 63;
    int lc = lane & 15, lg = lane >> 4;
    int wavegid = blockIdx.x * 4 + wid;   // 0..511
    float acc = 0.f;
    for (int base = wavegid * 4; base < N2; base += 512 * 4) {
        int row = base + lg;
        bf16x8 a = *reinterpret_cast<const bf16x8*>(rn + (size_t)row * DIM + lc * 8);
        bf16x8 b = *reinterpret_cast<const bf16x8*>(rn + (size_t)(row ^ B_ROWS) * DIM + lc * 8);
        float d = 0.f;
#pragma unroll
        for (int e = 0; e < 8; ++e)
            d += bf2f((unsigned short)a[e]) * bf2f((unsigned short)b[e]);
        float rs = part[(size_t)lc * N2 + row] + part[(size_t)(lc + 16) * N2 + row];
#pragma unroll
        for (int m = 1; m < 16; m <<= 1) {
            d  += __shfl_xor(d, m);
            rs += __shfl_xor(rs, m);
        }
        if (lc == 0)
            acc += LOG2F_FAST(rs - selfexp[row]) - d;
    }
#pragma unroll
    for (int m = 1; m < 64; m <<= 1) acc += __shfl_xor(acc, m);
    if (lane == 0) atomicAdd(out, acc * (LN2 / (float)N2));
}

extern "C" void kernel_launch(void* const* d_in, const int* in_sizes, int n_in,
                              void* d_out, int out_size, void* d_ws, size_t ws_size,
                              hipStream_t stream) {
    const float* zi = (const float*)d_in[0];
    const float* zj = (const float*)d_in[1];
    float* out = (float*)d_out;

    unsigned short* rn = (unsigned short*)d_ws;                       // 2 MiB
    float* part    = (float*)((char*)d_ws + (size_t)N2 * DIM * 2);    // 32*8192*4B = 1 MiB
    float* selfexp = part + 32 * N2;                                  // 32 KiB

    nk_normalize<<<2048, 256, 0, stream>>>(zi, zj, rn, selfexp, out);
    nk_simloss<<<1024, 256, 0, stream>>>(rn, part);
    nk_finalize<<<128, 256, 0, stream>>>(rn, part, selfexp, out);
}

// Round 12
// 101.156 us; speedup vs baseline: 1.6986x; 1.6986x over previous
//
#include <hip/hip_runtime.h>
#include <hip/hip_bf16.h>

#define B_ROWS 4096
#define N2     8192
#define DIM    128
#define LN2    0.6931471805599453f
// sqrt((1/T)*log2(e)): rn pre-scaled so the MFMA accumulator IS the exp2 arg.
#define S_SCALE 1.6986436f

typedef __attribute__((ext_vector_type(8))) short bf16x8;
typedef __attribute__((ext_vector_type(4))) float f32x4;

#if __has_builtin(__builtin_amdgcn_exp2f)
#define EXP2F(x) __builtin_amdgcn_exp2f(x)
#else
#define EXP2F(x) __expf((x) * LN2)   // native v_exp path
#endif
#if __has_builtin(__builtin_amdgcn_logf)
#define LOG2F_FAST(x) __builtin_amdgcn_logf(x)   // log2
#else
#define LOG2F_FAST(x) log2f(x)
#endif

static __device__ __forceinline__ unsigned short f2bf(float f) {
    union { float f; unsigned int u; } v; v.f = f;
    unsigned int u = v.u;
    return (unsigned short)((u + 0x7fffu + ((u >> 16) & 1u)) >> 16);
}
static __device__ __forceinline__ float bf2f(unsigned short s) {
    union { unsigned int u; float f; } v; v.u = ((unsigned int)s) << 16;
    return v.f;
}
static __device__ __forceinline__ void gload_lds16(const void* g, void* l) {
    __builtin_amdgcn_global_load_lds(
        (const __attribute__((address_space(1))) void*)g,
        (__attribute__((address_space(3))) void*)l, 16, 0, 0);
}

// K1: one wave per row -> L2-normalize, scale by S_SCALE, write bf16.
// selfexp[row] = exp2(<rn_row, rn_row>); zero out[0].
__global__ __launch_bounds__(256) void nk_normalize(
        const float* __restrict__ zi, const float* __restrict__ zj,
        unsigned short* __restrict__ rn, float* __restrict__ selfexp,
        float* __restrict__ out) {
    int gtid = blockIdx.x * 256 + threadIdx.x;
    if (gtid == 0) out[0] = 0.0f;
    int row  = gtid >> 6;
    int lane = threadIdx.x & 63;
    const float* src = (row < B_ROWS) ? (zi + (size_t)row * DIM)
                                      : (zj + (size_t)(row - B_ROWS) * DIM);
    float2 v = reinterpret_cast<const float2*>(src)[lane];
    float ss = v.x * v.x + v.y * v.y;
#pragma unroll
    for (int m = 1; m < 64; m <<= 1) ss += __shfl_xor(ss, m);
    float scale = S_SCALE / fmaxf(sqrtf(ss), 1e-8f);
    ushort2 o;
    o.x = f2bf(v.x * scale);
    o.y = f2bf(v.y * scale);
    reinterpret_cast<ushort2*>(rn + (size_t)row * DIM)[lane] = o;
    float a = bf2f(o.x), b = bf2f(o.y);
    float sd = a * a + b * b;
#pragma unroll
    for (int m = 1; m < 64; m <<= 1) sd += __shfl_xor(sd, m);
    if (lane == 0) selfexp[row] = EXP2F(sd);
}

// K2: part_out[bc][i] = sum_{j in chunk bc} exp2(acc_ij) (diag included).
// Grid 1024 = 32 row-panels(256 rows) x 32 col-chunks(256 cols). Block 256
// thr = 4 waves; wave = 64 rows (af[4][4]) -> halves per-CU LDS-read traffic
// vs the 32-row-wave shape. __launch_bounds__(256,3): the round-4-measured
// register allocation for this exact body (84 VGPR, no spill); (256,4)
// provably spills it (round 11: WRITE 155 MB). B staged to LDS in 64-col
// (16 KB) double-buffered tiles via global_load_lds with involutive XOR
// swizzle f(L)=L^(((L>>8)&7)<<4) on the per-lane GLOBAL source (LDS dest
// stays linear per-wave) and on the ds_read address. Strip body and T4
// counted-vmcnt barrier protocol VERBATIM from the round-10 kernel.
__global__ __launch_bounds__(256, 3) void nk_simloss(
        const unsigned short* __restrict__ rn, float* __restrict__ part_out) {
    __shared__ char lds[2][16384];
    const int tid = threadIdx.x;
    const int bi = blockIdx.x >> 5;   // row panel 0..31 (256 rows)
    const int bc = blockIdx.x & 31;   // col chunk 0..31 (256 cols)
    const int w = tid >> 6, lane = tid & 63;
    const int lc = lane & 15, lg = lane >> 4;
    const int i0 = bi * 256 + w * 64;

    // persistent A fragments: 64 rows x K=128
    const unsigned short* abase = rn + (size_t)(i0 + lc) * DIM + lg * 8;
    bf16x8 af[4][4];
#pragma unroll
    for (int mi = 0; mi < 4; ++mi)
#pragma unroll
        for (int ks = 0; ks < 4; ++ks)
            af[mi][ks] = *reinterpret_cast<const bf16x8*>(
                abase + (size_t)mi * 16 * DIM + ks * 32);

    const char* gsrc = (const char*)rn + (size_t)bc * 256 * 256;  // chunk's B panel

#define STAGE(b, t)                                                           \
    do {                                                                      \
        _Pragma("unroll") for (int k = 0; k < 4; ++k) {                       \
            int L  = k * 4096 + tid * 16;                                     \
            int Ls = L ^ (((L >> 8) & 7) << 4);                               \
            gload_lds16(gsrc + (size_t)(t) * 16384 + Ls,                      \
                        &lds[b][k * 4096 + (tid & 192) * 16]);                \
        }                                                                     \
    } while (0)

    float part[4][4];
#pragma unroll
    for (int mi = 0; mi < 4; ++mi)
#pragma unroll
        for (int p = 0; p < 4; ++p) part[mi][p] = 0.f;

    STAGE(0, 0);

#pragma unroll 1
    for (int t = 0; t < 4; ++t) {
        const int cur = t & 1;
        // (1) all waves done READING lds[cur^1] (previous tile) -> safe to
        // overwrite it. No vmcnt drain here.
        __builtin_amdgcn_s_barrier();
        __builtin_amdgcn_sched_barrier(0);
        if (t < 3) {
            STAGE(cur ^ 1, t + 1);   // 4 loads/thread now in flight
            // wait for tile t's 4 loads (issued last iter); t+1's 4 remain.
            asm volatile("s_waitcnt vmcnt(4)" ::: "memory");
        } else {
            asm volatile("s_waitcnt vmcnt(0)" ::: "memory");
        }
        // (2) every wave has retired ITS OWN tile-t loads -> lds[cur] fully
        // staged for everyone past this barrier.
        __builtin_amdgcn_s_barrier();
        __builtin_amdgcn_sched_barrier(0);
        const char* tb = lds[cur];
#pragma unroll
        for (int s = 0; s < 4; ++s) {          // 4 strips of 16 cols
            bf16x8 bf[4];
#pragma unroll
            for (int ks = 0; ks < 4; ++ks) {
                int r = s * 16 + lc;
                int a = r * 256 + ks * 64 + lg * 16;
                a ^= (r & 7) << 4;
                bf[ks] = *reinterpret_cast<const bf16x8*>(tb + a);
            }
            f32x4 acc[4];
#pragma unroll
            for (int mi = 0; mi < 4; ++mi) acc[mi] = (f32x4){0.f, 0.f, 0.f, 0.f};
#pragma unroll
            for (int ks = 0; ks < 4; ++ks)
#pragma unroll
                for (int mi = 0; mi < 4; ++mi)
                    acc[mi] = __builtin_amdgcn_mfma_f32_16x16x32_bf16(
                        af[mi][ks], bf[ks], acc[mi], 0, 0, 0);
#pragma unroll
            for (int mi = 0; mi < 4; ++mi)
#pragma unroll
                for (int p = 0; p < 4; ++p)
                    part[mi][p] += EXP2F(acc[mi][p]);
        }
    }
#undef STAGE

    // 16-lane reduce over cols (lc), store per-row partial for this chunk.
#pragma unroll
    for (int mi = 0; mi < 4; ++mi)
#pragma unroll
        for (int p = 0; p < 4; ++p) {
            float v = part[mi][p];
#pragma unroll
            for (int m = 1; m < 16; m <<= 1) v += __shfl_xor(v, m);
            if (lc == 0)
                part_out[(size_t)bc * N2 + i0 + mi * 16 + lg * 4 + p] = v;
        }
}

// K3: loss = (ln2/N2) * sum_i [ log2(sum_c part[c][i] - selfexp_i) - d_i ],
// d_i = <rn_i, rn_{i^B}> in the scaled metric (ln2*d = 2*pos).
// 32 partial planes: lane lc sums planes lc and lc+16 before the reduce.
__global__ __launch_bounds__(256) void nk_finalize(
        const unsigned short* __restrict__ rn, const float* __restrict__ part,
        const float* __restrict__ selfexp, float* __restrict__ out) {
    int wid = threadIdx.x >> 6, lane = threadIdx.x & 63;
    int lc = lane & 15, lg = lane >> 4;
    int wavegid = blockIdx.x * 4 + wid;   // 0..511
    float acc = 0.f;
    for (int base = wavegid * 4; base < N2; base += 512 * 4) {
        int row = base + lg;
        bf16x8 a = *reinterpret_cast<const bf16x8*>(rn + (size_t)row * DIM + lc * 8);
        bf16x8 b = *reinterpret_cast<const bf16x8*>(rn + (size_t)(row ^ B_ROWS) * DIM + lc * 8);
        float d = 0.f;
#pragma unroll
        for (int e = 0; e < 8; ++e)
            d += bf2f((unsigned short)a[e]) * bf2f((unsigned short)b[e]);
        float rs = part[(size_t)lc * N2 + row] + part[(size_t)(lc + 16) * N2 + row];
#pragma unroll
        for (int m = 1; m < 16; m <<= 1) {
            d  += __shfl_xor(d, m);
            rs += __shfl_xor(rs, m);
        }
        if (lc == 0)
            acc += LOG2F_FAST(rs - selfexp[row]) - d;
    }
#pragma unroll
    for (int m = 1; m < 64; m <<= 1) acc += __shfl_xor(acc, m);
    if (lane == 0) atomicAdd(out, acc * (LN2 / (float)N2));
}

extern "C" void kernel_launch(void* const* d_in, const int* in_sizes, int n_in,
                              void* d_out, int out_size, void* d_ws, size_t ws_size,
                              hipStream_t stream) {
    const float* zi = (const float*)d_in[0];
    const float* zj = (const float*)d_in[1];
    float* out = (float*)d_out;

    unsigned short* rn = (unsigned short*)d_ws;                       // 2 MiB
    float* part    = (float*)((char*)d_ws + (size_t)N2 * DIM * 2);    // 32*8192*4B = 1 MiB
    float* selfexp = part + 32 * N2;                                  // 32 KiB

    nk_normalize<<<2048, 256, 0, stream>>>(zi, zj, rn, selfexp, out);
    nk_simloss<<<1024, 256, 0, stream>>>(rn, part);
    nk_finalize<<<128, 256, 0, stream>>>(rn, part, selfexp, out);
}

// Round 13
// 93.635 us; speedup vs baseline: 1.8351x; 1.0803x over previous
//
#include <hip/hip_runtime.h>
#include <hip/hip_bf16.h>

#define B_ROWS 4096
#define N2     8192
#define DIM    128
#define LN2    0.6931471805599453f
// sqrt((1/T)*log2(e)): rn pre-scaled so the MFMA accumulator IS the exp2 arg.
#define S_SCALE 1.6986436f

typedef __attribute__((ext_vector_type(8))) short bf16x8;
typedef __attribute__((ext_vector_type(4))) float f32x4;

#if __has_builtin(__builtin_amdgcn_exp2f)
#define EXP2F(x) __builtin_amdgcn_exp2f(x)
#else
#define EXP2F(x) __expf((x) * LN2)   // native v_exp path
#endif
#if __has_builtin(__builtin_amdgcn_logf)
#define LOG2F_FAST(x) __builtin_amdgcn_logf(x)   // log2
#else
#define LOG2F_FAST(x) log2f(x)
#endif

static __device__ __forceinline__ unsigned short f2bf(float f) {
    union { float f; unsigned int u; } v; v.f = f;
    unsigned int u = v.u;
    return (unsigned short)((u + 0x7fffu + ((u >> 16) & 1u)) >> 16);
}
static __device__ __forceinline__ float bf2f(unsigned short s) {
    union { unsigned int u; float f; } v; v.u = ((unsigned int)s) << 16;
    return v.f;
}
static __device__ __forceinline__ void gload_lds16(const void* g, void* l) {
    __builtin_amdgcn_global_load_lds(
        (const __attribute__((address_space(1))) void*)g,
        (__attribute__((address_space(3))) void*)l, 16, 0, 0);
}

// K1: one wave per row -> L2-normalize, scale by S_SCALE, write bf16.
// selfexp[row] = exp2(<rn_row, rn_row>); zero rowsum and out.
__global__ __launch_bounds__(256) void nk_normalize(
        const float* __restrict__ zi, const float* __restrict__ zj,
        unsigned short* __restrict__ rn, float* __restrict__ selfexp,
        float* __restrict__ rowsum, float* __restrict__ out) {
    int gtid = blockIdx.x * 256 + threadIdx.x;
    if (gtid < N2) rowsum[gtid] = 0.0f;
    if (gtid == 0) out[0] = 0.0f;
    int row  = gtid >> 6;
    int lane = threadIdx.x & 63;
    const float* src = (row < B_ROWS) ? (zi + (size_t)row * DIM)
                                      : (zj + (size_t)(row - B_ROWS) * DIM);
    float2 v = reinterpret_cast<const float2*>(src)[lane];
    float ss = v.x * v.x + v.y * v.y;
#pragma unroll
    for (int m = 1; m < 64; m <<= 1) ss += __shfl_xor(ss, m);
    float scale = S_SCALE / fmaxf(sqrtf(ss), 1e-8f);
    ushort2 o;
    o.x = f2bf(v.x * scale);
    o.y = f2bf(v.y * scale);
    reinterpret_cast<ushort2*>(rn + (size_t)row * DIM)[lane] = o;
    float a = bf2f(o.x), b = bf2f(o.y);
    float sd = a * a + b * b;
#pragma unroll
    for (int m = 1; m < 64; m <<= 1) sd += __shfl_xor(sd, m);
    if (lane == 0) selfexp[row] = EXP2F(sd);
}

// K2 (triangular): sim is SYMMETRIC -> each unordered panel pair computed
// once; every exp2 value feeds rowsum[A-row] (row-reduce, as before) AND
// rowsum[B-col] (new col-reduce), except b==0 diagonal-panel blocks which
// are full tiles and contribute row-sums only. Grid 2112 = 64 a-panels x 33
// b-offsets; q = (a+b)&63; b==32 valid only for a<32 (others exit). Block
// 256 thr = 4 waves x 32 rows (af[2][4], the round-10 proven shape,
// launch_bounds (256,4), 32 KB LDS -> 4 blocks/CU). B-panel (128 cols)
// staged in two 64-col (16 KB) double-buffered LDS tiles via global_load_lds
// with involutive XOR swizzle f(L)=L^(((L>>8)&7)<<4) on the per-lane GLOBAL
// source (LDS dest linear per-wave) and the ds_read address. Strip body and
// T4 counted-vmcnt barrier protocol VERBATIM from round 10.
__global__ __launch_bounds__(256, 4) void nk_simloss(
        const unsigned short* __restrict__ rn, float* __restrict__ rowsum) {
    __shared__ char lds[2][16384];
    const int tid = threadIdx.x;
    const int a = blockIdx.x / 33;
    const int b = blockIdx.x - a * 33;
    if (b == 32 && a >= 32) return;   // uniform early exit, no barrier issued
    const int q = (a + b) & 63;       // B (column) panel
    const int w = tid >> 6, lane = tid & 63;
    const int lc = lane & 15, lg = lane >> 4;
    const int i0 = a * 128 + w * 32;

    // persistent A fragments: 32 rows x K=128
    const unsigned short* abase = rn + (size_t)(i0 + lc) * DIM + lg * 8;
    bf16x8 af[2][4];
#pragma unroll
    for (int mi = 0; mi < 2; ++mi)
#pragma unroll
        for (int ks = 0; ks < 4; ++ks)
            af[mi][ks] = *reinterpret_cast<const bf16x8*>(
                abase + (size_t)mi * 16 * DIM + ks * 32);

    const char* gsrc = (const char*)rn + (size_t)q * 128 * 256;  // B panel (128 rows)

#define STAGE(bbuf, t)                                                        \
    do {                                                                      \
        _Pragma("unroll") for (int k = 0; k < 4; ++k) {                       \
            int L  = k * 4096 + tid * 16;                                     \
            int Ls = L ^ (((L >> 8) & 7) << 4);                               \
            gload_lds16(gsrc + (size_t)(t) * 16384 + Ls,                      \
                        &lds[bbuf][k * 4096 + (tid & 192) * 16]);             \
        }                                                                     \
    } while (0)

    float part[2][4];
#pragma unroll
    for (int mi = 0; mi < 2; ++mi)
#pragma unroll
        for (int p = 0; p < 4; ++p) part[mi][p] = 0.f;

    STAGE(0, 0);

#pragma unroll 1
    for (int t = 0; t < 2; ++t) {
        const int cur = t & 1;
        // (1) all waves done READING lds[cur^1] -> safe to overwrite.
        __builtin_amdgcn_s_barrier();
        __builtin_amdgcn_sched_barrier(0);
        if (t < 1) {
            STAGE(cur ^ 1, t + 1);   // next tile's 4 loads in flight
            asm volatile("s_waitcnt vmcnt(4)" ::: "memory");
        } else {
            asm volatile("s_waitcnt vmcnt(0)" ::: "memory");
        }
        // (2) every wave's own tile-t loads retired -> lds[cur] staged.
        __builtin_amdgcn_s_barrier();
        __builtin_amdgcn_sched_barrier(0);
        const char* tb = lds[cur];
        float colacc[4] = {0.f, 0.f, 0.f, 0.f};   // per-strip col partials
#pragma unroll
        for (int s = 0; s < 4; ++s) {          // 4 strips of 16 cols
            bf16x8 bf[4];
#pragma unroll
            for (int ks = 0; ks < 4; ++ks) {
                int r = s * 16 + lc;
                int ad = r * 256 + ks * 64 + lg * 16;
                ad ^= (r & 7) << 4;
                bf[ks] = *reinterpret_cast<const bf16x8*>(tb + ad);
            }
            f32x4 acc[2];
#pragma unroll
            for (int mi = 0; mi < 2; ++mi) acc[mi] = (f32x4){0.f, 0.f, 0.f, 0.f};
#pragma unroll
            for (int ks = 0; ks < 4; ++ks)
#pragma unroll
                for (int mi = 0; mi < 2; ++mi)
                    acc[mi] = __builtin_amdgcn_mfma_f32_16x16x32_bf16(
                        af[mi][ks], bf[ks], acc[mi], 0, 0, 0);
#pragma unroll
            for (int mi = 0; mi < 2; ++mi)
#pragma unroll
                for (int p = 0; p < 4; ++p) {
                    float e = EXP2F(acc[mi][p]);
                    part[mi][p] += e;
                    colacc[s]   += e;
                }
        }
        // col-reduce flush for this tile (b>0 only; b==0 would double-count).
        if (b != 0) {
#pragma unroll
            for (int s = 0; s < 4; ++s) {
                float cv = colacc[s];
                cv += __shfl_xor(cv, 16);
                cv += __shfl_xor(cv, 32);
                if (lane < 16)
                    atomicAdd(&rowsum[q * 128 + t * 64 + s * 16 + lc], cv);
            }
        }
    }
#undef STAGE

    // 16-lane reduce over cols (lc), one atomic per row per wave.
#pragma unroll
    for (int mi = 0; mi < 2; ++mi)
#pragma unroll
        for (int p = 0; p < 4; ++p) {
            float v = part[mi][p];
#pragma unroll
            for (int m = 1; m < 16; m <<= 1) v += __shfl_xor(v, m);
            if (lc == 0)
                atomicAdd(&rowsum[i0 + mi * 16 + lg * 4 + p], v);
        }
}

// K3: loss = (ln2/N2) * sum_i [ log2(rowsum_i - selfexp_i) - d_i ],
// d_i = <rn_i, rn_{i^B}> in the scaled metric (ln2*d = 2*pos).
__global__ __launch_bounds__(256) void nk_finalize(
        const unsigned short* __restrict__ rn, const float* __restrict__ rowsum,
        const float* __restrict__ selfexp, float* __restrict__ out) {
    int wid = threadIdx.x >> 6, lane = threadIdx.x & 63;
    int lc = lane & 15, lg = lane >> 4;
    int wavegid = blockIdx.x * 4 + wid;   // 0..511
    float acc = 0.f;
    for (int base = wavegid * 4; base < N2; base += 512 * 4) {
        int row = base + lg;
        bf16x8 a = *reinterpret_cast<const bf16x8*>(rn + (size_t)row * DIM + lc * 8);
        bf16x8 b = *reinterpret_cast<const bf16x8*>(rn + (size_t)(row ^ B_ROWS) * DIM + lc * 8);
        float d = 0.f;
#pragma unroll
        for (int e = 0; e < 8; ++e)
            d += bf2f((unsigned short)a[e]) * bf2f((unsigned short)b[e]);
#pragma unroll
        for (int m = 1; m < 16; m <<= 1) d += __shfl_xor(d, m);
        if (lc == 0)
            acc += LOG2F_FAST(rowsum[row] - selfexp[row]) - d;
    }
#pragma unroll
    for (int m = 1; m < 64; m <<= 1) acc += __shfl_xor(acc, m);
    if (lane == 0) atomicAdd(out, acc * (LN2 / (float)N2));
}

extern "C" void kernel_launch(void* const* d_in, const int* in_sizes, int n_in,
                              void* d_out, int out_size, void* d_ws, size_t ws_size,
                              hipStream_t stream) {
    const float* zi = (const float*)d_in[0];
    const float* zj = (const float*)d_in[1];
    float* out = (float*)d_out;

    unsigned short* rn = (unsigned short*)d_ws;                       // 2 MiB
    float* rowsum  = (float*)((char*)d_ws + (size_t)N2 * DIM * 2);    // 32 KiB
    float* selfexp = rowsum + N2;                                     // 32 KiB

    nk_normalize<<<2048, 256, 0, stream>>>(zi, zj, rn, selfexp, rowsum, out);
    nk_simloss<<<2112, 256, 0, stream>>>(rn, rowsum);
    nk_finalize<<<128, 256, 0, stream>>>(rn, rowsum, selfexp, out);
}

// Round 14
// 80.888 us; speedup vs baseline: 2.1242x; 1.1576x over previous
//
#include <hip/hip_runtime.h>
#include <hip/hip_bf16.h>

#define B_ROWS 4096
#define N2     8192
#define DIM    128
#define LN2    0.6931471805599453f
// sqrt((1/T)*log2(e)): rn pre-scaled so the MFMA accumulator IS the exp2 arg.
#define S_SCALE 1.6986436f
// exp2(S_SCALE^2) = exp2(2*log2(e)) = e^2: the GEMM's diagonal term
// (f32-normalized self-dot is exactly S_SCALE^2; bf16 rounding shifts it by
// ~±0.005 out of a ~8300 rowsum -> ~6e-7 in the log -> negligible).
#define PDIAG 7.3890560989f

typedef __attribute__((ext_vector_type(8))) short bf16x8;
typedef __attribute__((ext_vector_type(4))) float f32x4;

#if __has_builtin(__builtin_amdgcn_exp2f)
#define EXP2F(x) __builtin_amdgcn_exp2f(x)
#else
#define EXP2F(x) __expf((x) * LN2)   // native v_exp path
#endif
#if __has_builtin(__builtin_amdgcn_logf)
#define LOG2F_FAST(x) __builtin_amdgcn_logf(x)   // log2
#else
#define LOG2F_FAST(x) log2f(x)
#endif

static __device__ __forceinline__ unsigned short f2bf(float f) {
    union { float f; unsigned int u; } v; v.f = f;
    unsigned int u = v.u;
    return (unsigned short)((u + 0x7fffu + ((u >> 16) & 1u)) >> 16);
}
static __device__ __forceinline__ float bf2f(unsigned short s) {
    union { unsigned int u; float f; } v; v.u = ((unsigned int)s) << 16;
    return v.f;
}
static __device__ __forceinline__ void gload_lds16(const void* g, void* l) {
    __builtin_amdgcn_global_load_lds(
        (const __attribute__((address_space(1))) void*)g,
        (__attribute__((address_space(3))) void*)l, 16, 0, 0);
}

// K1: one wave per PAIR (r, r+B): L2-normalize both rows, scale by S_SCALE,
// write bf16; posv[r] = <z_i, z_j> * s_i * s_j (the scaled positive-pair dot,
// computed from registers -> K3 no longer re-reads rn). Zero out[0].
__global__ __launch_bounds__(256) void nk_normpair(
        const float* __restrict__ zi, const float* __restrict__ zj,
        unsigned short* __restrict__ rn, float* __restrict__ posv,
        float* __restrict__ out) {
    if (blockIdx.x == 0 && threadIdx.x == 0) out[0] = 0.0f;
    int w = threadIdx.x >> 6, lane = threadIdx.x & 63;
    int r = blockIdx.x * 4 + w;                 // pair index 0..4095
    float2 a = reinterpret_cast<const float2*>(zi + (size_t)r * DIM)[lane];
    float2 b = reinterpret_cast<const float2*>(zj + (size_t)r * DIM)[lane];
    float ssi = a.x * a.x + a.y * a.y;
    float ssj = b.x * b.x + b.y * b.y;
    float dd  = a.x * b.x + a.y * b.y;
#pragma unroll
    for (int m = 1; m < 64; m <<= 1) {
        ssi += __shfl_xor(ssi, m);
        ssj += __shfl_xor(ssj, m);
        dd  += __shfl_xor(dd,  m);
    }
    float si = S_SCALE / fmaxf(sqrtf(ssi), 1e-8f);
    float sj = S_SCALE / fmaxf(sqrtf(ssj), 1e-8f);
    ushort2 oi, oj;
    oi.x = f2bf(a.x * si); oi.y = f2bf(a.y * si);
    oj.x = f2bf(b.x * sj); oj.y = f2bf(b.y * sj);
    reinterpret_cast<ushort2*>(rn + (size_t)r * DIM)[lane] = oi;
    reinterpret_cast<ushort2*>(rn + (size_t)(r + B_ROWS) * DIM)[lane] = oj;
    if (lane == 0) posv[r] = dd * si * sj;
}

// K2: part_out[bc][i] = sum_{j in chunk bc} exp2(acc_ij) (diag included).
// Grid 1024 = 64 row-panels(128) x 16 col-chunks(512). Block 256 thr = 4
// waves; wave = 32 rows. B staged to LDS in 64-col (16 KB) double-buffered
// tiles via global_load_lds with involutive XOR swizzle f(L)=L^(((L>>8)&7)<<4)
// applied to the per-lane GLOBAL source (LDS dest stays linear per-wave) and
// to the ds_read address. BYTE-IDENTICAL to the round-10 kernel (90.9 us);
// T4 counted-vmcnt raw-barrier protocol.
__global__ __launch_bounds__(256, 4) void nk_simloss(
        const unsigned short* __restrict__ rn, float* __restrict__ part_out) {
    __shared__ char lds[2][16384];
    const int tid = threadIdx.x;
    const int bi = blockIdx.x >> 4;   // row panel 0..63 (128 rows)
    const int bc = blockIdx.x & 15;   // col chunk 0..15 (512 cols)
    const int w = tid >> 6, lane = tid & 63;
    const int lc = lane & 15, lg = lane >> 4;
    const int i0 = bi * 128 + w * 32;

    // persistent A fragments: 32 rows x K=128
    const unsigned short* abase = rn + (size_t)(i0 + lc) * DIM + lg * 8;
    bf16x8 af[2][4];
#pragma unroll
    for (int mi = 0; mi < 2; ++mi)
#pragma unroll
        for (int ks = 0; ks < 4; ++ks)
            af[mi][ks] = *reinterpret_cast<const bf16x8*>(
                abase + (size_t)mi * 16 * DIM + ks * 32);

    const char* gsrc = (const char*)rn + (size_t)bc * 512 * 256;  // chunk's B panel

#define STAGE(b, t)                                                           \
    do {                                                                      \
        _Pragma("unroll") for (int k = 0; k < 4; ++k) {                       \
            int L  = k * 4096 + tid * 16;                                     \
            int Ls = L ^ (((L >> 8) & 7) << 4);                               \
            gload_lds16(gsrc + (size_t)(t) * 16384 + Ls,                      \
                        &lds[b][k * 4096 + (tid & 192) * 16]);                \
        }                                                                     \
    } while (0)

    float part[2][4];
#pragma unroll
    for (int mi = 0; mi < 2; ++mi)
#pragma unroll
        for (int p = 0; p < 4; ++p) part[mi][p] = 0.f;

    STAGE(0, 0);

#pragma unroll 1
    for (int t = 0; t < 8; ++t) {
        const int cur = t & 1;
        // (1) all waves done READING lds[cur^1] (previous tile) -> safe to
        // overwrite it. No vmcnt drain here.
        __builtin_amdgcn_s_barrier();
        __builtin_amdgcn_sched_barrier(0);
        if (t < 7) {
            STAGE(cur ^ 1, t + 1);   // 4 loads/thread now in flight
            // wait for tile t's 4 loads (issued last iter); t+1's 4 remain.
            asm volatile("s_waitcnt vmcnt(4)" ::: "memory");
        } else {
            asm volatile("s_waitcnt vmcnt(0)" ::: "memory");
        }
        // (2) every wave has retired ITS OWN tile-t loads -> lds[cur] fully
        // staged for everyone past this barrier.
        __builtin_amdgcn_s_barrier();
        __builtin_amdgcn_sched_barrier(0);
        const char* tb = lds[cur];
#pragma unroll
        for (int s = 0; s < 4; ++s) {          // 4 strips of 16 cols
            bf16x8 bf[4];
#pragma unroll
            for (int ks = 0; ks < 4; ++ks) {
                int r = s * 16 + lc;
                int a = r * 256 + ks * 64 + lg * 16;
                a ^= (r & 7) << 4;
                bf[ks] = *reinterpret_cast<const bf16x8*>(tb + a);
            }
            f32x4 acc[2];
#pragma unroll
            for (int mi = 0; mi < 2; ++mi) acc[mi] = (f32x4){0.f, 0.f, 0.f, 0.f};
#pragma unroll
            for (int ks = 0; ks < 4; ++ks)
#pragma unroll
                for (int mi = 0; mi < 2; ++mi)
                    acc[mi] = __builtin_amdgcn_mfma_f32_16x16x32_bf16(
                        af[mi][ks], bf[ks], acc[mi], 0, 0, 0);
#pragma unroll
            for (int mi = 0; mi < 2; ++mi)
#pragma unroll
                for (int p = 0; p < 4; ++p)
                    part[mi][p] += EXP2F(acc[mi][p]);
        }
    }
#undef STAGE

    // 16-lane reduce over cols (lc), store per-row partial for this chunk.
#pragma unroll
    for (int mi = 0; mi < 2; ++mi)
#pragma unroll
        for (int p = 0; p < 4; ++p) {
            float v = part[mi][p];
#pragma unroll
            for (int m = 1; m < 16; m <<= 1) v += __shfl_xor(v, m);
            if (lc == 0)
                part_out[(size_t)bc * N2 + i0 + mi * 16 + lg * 4 + p] = v;
        }
}

// K3 (trivial now): loss = (ln2/N2) * sum_r [ log2(sum_c part[c][r] - e^2)
//                                             - posv[r & (B-1)] ].
// 32 blocks x 256 thr, one row per thread; 16 strided L2-resident reads.
__global__ __launch_bounds__(256) void nk_finalize(
        const float* __restrict__ part, const float* __restrict__ posv,
        float* __restrict__ out) {
    __shared__ float red[256];
    int row = blockIdx.x * 256 + threadIdx.x;   // 0..8191
    float rs = 0.f;
#pragma unroll
    for (int c = 0; c < 16; ++c) rs += part[(size_t)c * N2 + row];
    float acc = LOG2F_FAST(rs - PDIAG) - posv[row & (B_ROWS - 1)];
    red[threadIdx.x] = acc;
    __syncthreads();
    for (int off = 128; off > 0; off >>= 1) {
        if (threadIdx.x < off) red[threadIdx.x] += red[threadIdx.x + off];
        __syncthreads();
    }
    if (threadIdx.x == 0) atomicAdd(out, red[0] * (LN2 / (float)N2));
}

extern "C" void kernel_launch(void* const* d_in, const int* in_sizes, int n_in,
                              void* d_out, int out_size, void* d_ws, size_t ws_size,
                              hipStream_t stream) {
    const float* zi = (const float*)d_in[0];
    const float* zj = (const float*)d_in[1];
    float* out = (float*)d_out;

    unsigned short* rn = (unsigned short*)d_ws;                       // 2 MiB
    float* part = (float*)((char*)d_ws + (size_t)N2 * DIM * 2);       // 16*8192*4B = 512 KiB
    float* posv = part + 16 * N2;                                     // 16 KiB

    nk_normpair<<<1024, 256, 0, stream>>>(zi, zj, rn, posv, out);
    nk_simloss<<<1024, 256, 0, stream>>>(rn, part);
    nk_finalize<<<32, 256, 0, stream>>>(part, posv, out);
}